// Round 20
// baseline (565.161 us; speedup 1.0000x reference)
//
#include <hip/hip_runtime.h>
#include <stdint.h>

#define NN 100000
#define EE 1600000
#define DD 256
#define GB0 1563            // gemm blocks: (NN+63)/64
#define NFILL 1024          // fill blocks (NSUB*8)
#define NSUB 128

typedef __bf16 bf16;
typedef __attribute__((ext_vector_type(8))) __bf16 bf16x8;
typedef __attribute__((ext_vector_type(4))) float f32x4;
typedef __attribute__((ext_vector_type(4))) unsigned int u32x4;
typedef __attribute__((ext_vector_type(8))) unsigned short u16x8;

typedef __attribute__((address_space(1))) const unsigned int g_u32c;
typedef __attribute__((address_space(3))) unsigned int lds_u32;

__device__ __forceinline__ float bflo(unsigned int u) {
    union { unsigned int u; float f; } x; x.u = u << 16; return x.f;
}
__device__ __forceinline__ float bfhi(unsigned int u) {
    union { unsigned int u; float f; } x; x.u = u & 0xFFFF0000u; return x.f;
}
__device__ __forceinline__ unsigned short f2bf(float f) {
    return __builtin_bit_cast(unsigned short, (__bf16)f);
}

// ---------------------------------------------------------------------------
// fillprep: blocks [0,NFILL) = direct-slot CSR fill (dst-partitioned by XCD,
// scan-free: atomic cursor IS the degree); blocks [NFILL,NFILL+193) = weight
// transpose-cvt (192) + mask probe (1).
// ---------------------------------------------------------------------------
__global__ __launch_bounds__(256) void fillprep_k(
    const int* __restrict__ src, const int* __restrict__ dst,
    int* __restrict__ cnt, int* __restrict__ cs,
    const float* __restrict__ W0, const float* __restrict__ W1,
    const float* __restrict__ W2, bf16* __restrict__ T0,
    bf16* __restrict__ T1, bf16* __restrict__ T2,
    const unsigned int* __restrict__ m, int* __restrict__ flag) {
    int b = blockIdx.x;
    if (b < NFILL) {
        int prt = b & 7;
        int sub = b >> 3;
        int lo = prt * (NN >> 3);
        int hi = (prt == 7) ? NN : lo + (NN >> 3);
        const int per = EE / NSUB;
        int e0 = sub * per;
        int e1 = (sub == NSUB - 1) ? EE : e0 + per;
        for (int e = e0 + threadIdx.x; e < e1; e += 256) {
            int d = dst[e];
            if (d >= lo && d < hi) {
                int s = src[e];
                int slot = atomicAdd(&cnt[d], 1);
                if (slot < 64) cs[(d << 6) + slot] = s;   // P(overflow) ~ 5e-14
            }
        }
        return;
    }
    b -= NFILL;
    if (b == 192) {
        if (threadIdx.x < 64) {
            unsigned int v = m[threadIdx.x];
            int bad = (v > 1u && v != 0x3F800000u) ? 1 : 0;
            unsigned long long bl = __ballot(bad);
            if (threadIdx.x == 0) *flag = (bl != 0ull) ? 1 : 0;
        }
        return;
    }
    const float* W = b < 64 ? W0 : (b < 128 ? W1 : W2);
    bf16*       T  = b < 64 ? T0 : (b < 128 ? T1 : T2);
    int bb = b & 63;
    __shared__ float tile[32][33];
    int bx = bb & 7, by = bb >> 3;
    int tx = threadIdx.x & 31, ty = threadIdx.x >> 5;
    #pragma unroll
    for (int r = 0; r < 32; r += 8)
        tile[ty + r][tx] = W[(size_t)(by * 32 + ty + r) * DD + bx * 32 + tx];
    __syncthreads();
    #pragma unroll
    for (int r = 0; r < 32; r += 8)
        T[(size_t)(bx * 32 + ty + r) * DD + by * 32 + tx] = (bf16)tile[tx][ty + r];
}

// ---------------------------------------------------------------------------
// GEMM body: 64x256 tile, BK=32, DOUBLE-BUFFERED LDS, ONE barrier per K-step
// (T3 minimum 2-phase: issue next-step global_load_lds, compute current,
// single __syncthreads whose vmcnt(0) lands after the MFMA phase).
// XOR swizzle c^(row&3) within 4-chunk rows (rule 21: linear LDS dest +
// swizzled global source; reads use lk^(lr&3)).
// EPI 1: +bias, relu, dropout(mask) -> bf16.  EPI 2: +bias, *z -> fp32 nt.
// ---------------------------------------------------------------------------
template <int EPI, int F32A>
__device__ __forceinline__ void gemm_body(
    const void* __restrict__ Ap, const bf16* __restrict__ Wt,
    const float* __restrict__ bias, const void* __restrict__ mask,
    const int* __restrict__ flagp, const float* __restrict__ z,
    void* __restrict__ outp, bf16* AsBase, bf16* BsBase, int m0) {
    int tid = threadIdx.x;
    int wid = tid >> 6, lane = tid & 63;
    int lr = lane & 15, lk = lane >> 4;

    // per-thread staging coords (BK=32: A 256 chunks = 1/thr, B 1024 = 4/thr)
    int arow = tid >> 2, ac = tid & 3;
    int acg  = ac ^ (arow & 3);
    int agr = m0 + arow; if (agr > NN - 1) agr = NN - 1;

    auto stage = [&](int buf, int k0) {
        bf16* As = AsBase + buf * (64 * 32);
        bf16* Bs = BsBase + buf * (256 * 32);
        if (F32A) {
            const float* sp = (const float*)Ap + (size_t)agr * DD + k0 + ac * 8;
            float4 v0 = *(const float4*)sp;
            float4 v1 = *(const float4*)(sp + 4);
            u16x8 o = { f2bf(v0.x), f2bf(v0.y), f2bf(v0.z), f2bf(v0.w),
                        f2bf(v1.x), f2bf(v1.y), f2bf(v1.z), f2bf(v1.w) };
            *(u16x8*)(As + arow * 32 + acg * 8) = o;
        } else {
            __builtin_amdgcn_global_load_lds(
                (g_u32c*)((const bf16*)Ap + (size_t)agr * DD + k0 + acg * 8),
                (lds_u32*)(As + (size_t)tid * 8), 16, 0, 0);
        }
        #pragma unroll
        for (int i = 0; i < 4; i++) {
            int f = i * 256 + tid;
            int row = f >> 2;
            int cg  = (f & 3) ^ (row & 3);
            __builtin_amdgcn_global_load_lds(
                (g_u32c*)(Wt + (size_t)row * DD + k0 + cg * 8),
                (lds_u32*)(Bs + (size_t)f * 8), 16, 0, 0);
        }
    };

    f32x4 acc[4][4] = {};

    stage(0, 0);
    __syncthreads();
    #pragma unroll
    for (int step = 0; step < 8; step++) {
        int cur = step & 1;
        if (step < 7) stage(cur ^ 1, (step + 1) * 32);   // async into other buf
        const bf16* As = AsBase + cur * (64 * 32);
        const bf16* Bs = BsBase + cur * (256 * 32);
        bf16x8 af[4], bfr[4];
        int rc = (lk ^ (lr & 3)) * 8;
        #pragma unroll
        for (int mi = 0; mi < 4; mi++)
            af[mi] = *(const bf16x8*)(As + (mi * 16 + lr) * 32 + rc);
        #pragma unroll
        for (int ni = 0; ni < 4; ni++)
            bfr[ni] = *(const bf16x8*)(Bs + (wid * 64 + ni * 16 + lr) * 32 + rc);
        #pragma unroll
        for (int mi = 0; mi < 4; mi++)
            #pragma unroll
            for (int ni = 0; ni < 4; ni++)
                acc[mi][ni] = __builtin_amdgcn_mfma_f32_16x16x32_bf16(
                    bfr[ni], af[mi], acc[mi][ni], 0, 0, 0);   // swapped operands
        __syncthreads();   // drains this step's stage (vmcnt0) after MFMA phase
    }

    int bm = (EPI == 1) ? *flagp : 0;
    #pragma unroll
    for (int mi = 0; mi < 4; mi++) {
        int gr = m0 + mi * 16 + lr;
        if (gr >= NN) continue;
        #pragma unroll
        for (int ni = 0; ni < 4; ni++) {
            int gc = wid * 64 + ni * 16 + lk * 4;
            size_t idx = (size_t)gr * DD + gc;
            float4 b4 = *(const float4*)(bias + gc);
            float v0 = acc[mi][ni][0] + b4.x;
            float v1 = acc[mi][ni][1] + b4.y;
            float v2 = acc[mi][ni][2] + b4.z;
            float v3 = acc[mi][ni][3] + b4.w;
            if (EPI == 1) {
                v0 = fmaxf(v0, 0.f); v1 = fmaxf(v1, 0.f);
                v2 = fmaxf(v2, 0.f); v3 = fmaxf(v3, 0.f);
                if (bm) {
                    uchar4 u = *(const uchar4*)((const unsigned char*)mask + idx);
                    v0 *= u.x ? 2.f : 0.f; v1 *= u.y ? 2.f : 0.f;
                    v2 *= u.z ? 2.f : 0.f; v3 *= u.w ? 2.f : 0.f;
                } else {
                    uint4 u = *(const uint4*)((const unsigned int*)mask + idx);
                    v0 *= u.x ? 2.f : 0.f; v1 *= u.y ? 2.f : 0.f;
                    v2 *= u.z ? 2.f : 0.f; v3 *= u.w ? 2.f : 0.f;
                }
                ushort4 o = { f2bf(v0), f2bf(v1), f2bf(v2), f2bf(v3) };
                *(ushort4*)((unsigned short*)outp + idx) = o;
            } else {
                f32x4 zz = __builtin_nontemporal_load((const f32x4*)(z + idx));
                f32x4 o = { v0 * zz.x, v1 * zz.y, v2 * zz.z, v3 * zz.w };
                __builtin_nontemporal_store(o, (f32x4*)((float*)outp + idx));
            }
        }
    }
}

__global__ __launch_bounds__(256) void gemm0_k(
    const float* __restrict__ omega, const bf16* __restrict__ Wt,
    const float* __restrict__ bias, const void* __restrict__ mask,
    const int* __restrict__ flagp, bf16* __restrict__ outp) {
    __shared__ __align__(16) bf16 As[2 * 64 * 32];    // 8 KB
    __shared__ __align__(16) bf16 Bs[2 * 256 * 32];   // 32 KB
    int m0 = blockIdx.x * 64;
    if (m0 >= NN) return;
    gemm_body<1, 1>(omega, Wt, bias, mask, flagp, nullptr, outp, As, Bs, m0);
}

template <int ID, int EPI>
__global__ __launch_bounds__(256) void gemm_k(
    const bf16* __restrict__ Ap, const bf16* __restrict__ Wt,
    const float* __restrict__ bias, const void* __restrict__ mask,
    const int* __restrict__ flagp, const float* __restrict__ z,
    void* __restrict__ outp) {
    __shared__ __align__(16) bf16 As[2 * 64 * 32];
    __shared__ __align__(16) bf16 Bs[2 * 256 * 32];
    int m0 = blockIdx.x * 64;
    if (m0 >= NN) return;
    gemm_body<EPI, 0>(Ap, Wt, bias, mask, flagp, z, outp, As, Bs, m0);
}

// ---------------------------------------------------------------------------
// Slot-gather: out[n,:] = dinv[n] * ( sum_s dinv[s]*X[s,:] + dinv[n]*X[n,:] ).
// dinv on the fly: rsqrtf(cnt+1). cnt[n] <= 63 entries at cs[n*64..];
// proven depth-4 pipeline; self-loop in fp32 epilogue.
// ---------------------------------------------------------------------------
#define AGG_GET(J, UVAR, MVAR)                                                   \
    {                                                                            \
        int _i = 2 * (J) + half;                                                 \
        int _s = __shfl(sl, _i & 63);                                            \
        float _w = __shfl(wl, _i & 63);                                          \
        MVAR = (_i < nume) ? _w : 0.f;                                           \
        UVAR = *(const u32x4*)(tb + (((size_t)(unsigned)_s) << 9) + lcoff);      \
    }
#define AGG_FMA(UVAR, MVAR)                                                      \
    {                                                                            \
        acc[0] = fmaf(MVAR, bflo(UVAR.x), acc[0]);                               \
        acc[1] = fmaf(MVAR, bfhi(UVAR.x), acc[1]);                               \
        acc[2] = fmaf(MVAR, bflo(UVAR.y), acc[2]);                               \
        acc[3] = fmaf(MVAR, bfhi(UVAR.y), acc[3]);                               \
        acc[4] = fmaf(MVAR, bflo(UVAR.z), acc[4]);                               \
        acc[5] = fmaf(MVAR, bfhi(UVAR.z), acc[5]);                               \
        acc[6] = fmaf(MVAR, bflo(UVAR.w), acc[6]);                               \
        acc[7] = fmaf(MVAR, bfhi(UVAR.w), acc[7]);                               \
    }

__global__ __launch_bounds__(256) void agg_k(
    const bf16* __restrict__ t, const int* __restrict__ cnt,
    const int* __restrict__ cs, bf16* __restrict__ out) {
    int node = blockIdx.x * 4 + (threadIdx.x >> 6);
    if (node >= NN) return;
    int lane = threadIdx.x & 63;
    int half = lane >> 5;
    int lc = lane & 31;
    int cn = cnt[node];
    int nume = cn > 63 ? 63 : cn;

    float acc[8] = {};
    const char* tb = (const char*)t;
    size_t lcoff = (size_t)(lc << 4);

    if (nume > 0) {
        int base = node << 6;
        int sl = 0; float wl = 0.f;
        if (lane < nume) {
            sl = __builtin_nontemporal_load(cs + base + lane);
            wl = rsqrtf((float)(cnt[sl] + 1));
        }
        int nit = (nume + 1) >> 1;

        u32x4 ua, ub, uc, ud;
        float ma, mb, mc, md;
        AGG_GET(0, ua, ma);
        AGG_GET(1, ub, mb);
        AGG_GET(2, uc, mc);
        int j = 0;
        for (; j + 3 < nit; j += 4) {
            AGG_GET(j + 3, ud, md); AGG_FMA(ua, ma);
            AGG_GET(j + 4, ua, ma); AGG_FMA(ub, mb);
            AGG_GET(j + 5, ub, mb); AGG_FMA(uc, mc);
            AGG_GET(j + 6, uc, mc); AGG_FMA(ud, md);
        }
        int rem = nit - j;
        if (rem > 0) AGG_FMA(ua, ma);
        if (rem > 1) AGG_FMA(ub, mb);
        if (rem > 2) AGG_FMA(uc, mc);
    }

    float dn = rsqrtf((float)(cn + 1));
    #pragma unroll
    for (int i = 0; i < 8; i++) acc[i] += __shfl_xor(acc[i], 32);
    if (half == 0) {
        u32x4 u = *(const u32x4*)(tb + (((size_t)(unsigned)node) << 9) + lcoff);
        acc[0] = fmaf(dn, bflo(u.x), acc[0]);
        acc[1] = fmaf(dn, bfhi(u.x), acc[1]);
        acc[2] = fmaf(dn, bflo(u.y), acc[2]);
        acc[3] = fmaf(dn, bfhi(u.y), acc[3]);
        acc[4] = fmaf(dn, bflo(u.z), acc[4]);
        acc[5] = fmaf(dn, bfhi(u.z), acc[5]);
        acc[6] = fmaf(dn, bflo(u.w), acc[6]);
        acc[7] = fmaf(dn, bfhi(u.w), acc[7]);
        #pragma unroll
        for (int i = 0; i < 8; i++) acc[i] *= dn;
        u16x8 o = { f2bf(acc[0]), f2bf(acc[1]), f2bf(acc[2]), f2bf(acc[3]),
                    f2bf(acc[4]), f2bf(acc[5]), f2bf(acc[6]), f2bf(acc[7]) };
        __builtin_nontemporal_store(o, (u16x8*)((unsigned short*)out + (size_t)node * DD + lc * 8));
    }
}

// ---------------------------------------------------------------------------
extern "C" void kernel_launch(void* const* d_in, const int* in_sizes, int n_in,
                              void* d_out, int out_size, void* d_ws, size_t ws_size,
                              hipStream_t stream) {
    const float* z     = (const float*)d_in[0];
    const float* omega = (const float*)d_in[1];
    const int*   eidx  = (const int*)d_in[2];
    const float* W_lin = (const float*)d_in[3];
    const float* b_lin = (const float*)d_in[4];
    const float* W_g1  = (const float*)d_in[5];
    const float* b_g1  = (const float*)d_in[6];
    const float* W_g2  = (const float*)d_in[7];
    const float* b_g2  = (const float*)d_in[8];
    const void*  mask1 = d_in[9];
    const void*  mask2 = d_in[10];

    const int* e_src = eidx;
    const int* e_dst = eidx + EE;

    char* p = (char*)d_ws;
    size_t off = 0;
    auto alloc = [&](size_t bytes) -> char* {
        char* r = p + off;
        off = (off + bytes + 255) & ~(size_t)255;
        return r;
    };
    int*   flag = (int*)  alloc(4);
    int*   cnt  = (int*)  alloc((size_t)NN * 4);
    int*   cs   = (int*)  alloc((size_t)NN * 64 * 4);   // 25.6 MB slots
    bf16*  WtL  = (bf16*) alloc((size_t)DD * DD * 2);
    bf16*  Wt1  = (bf16*) alloc((size_t)DD * DD * 2);
    bf16*  Wt2  = (bf16*) alloc((size_t)DD * DD * 2);
    const size_t NBH = (size_t)NN * DD * 2;      // 51.2 MB bf16 slab
    bf16*  S1   = (bf16*) alloc(NBH);
    bf16*  S2   = (bf16*) alloc(NBH);

    // --- zero degree counters; fill CSR + weight-cvt + probe (one dispatch) ---
    (void)hipMemsetAsync(cnt, 0, (size_t)NN * 4, stream);
    fillprep_k<<<NFILL + 193, 256, 0, stream>>>(e_src, e_dst, cnt, cs,
                                                W_lin, W_g1, W_g2, WtL, Wt1, Wt2,
                                                (const unsigned int*)mask1, flag);

    // --- pipeline ---
    // h0 = dropout(relu(omega @ W_lin + b_lin))           omega(f32) -> S1
    gemm0_k<<<GB0, 256, 0, stream>>>(omega, WtL, b_lin, mask1, flag, S1);
    // g1 = dinv-weighted gather of S1 (+ self)            S1 -> S2
    agg_k<<<NN / 4, 256, 0, stream>>>(S1, cnt, cs, S2);
    // h1 = dropout(relu(g1 @ W_g1 + b_g1))                S2 -> S1
    gemm_k<1, 1><<<GB0, 256, 0, stream>>>(S2, Wt1, b_g1, mask2, flag, nullptr, S1);
    // g2 = dinv-weighted gather of S1 (+ self)            S1 -> S2
    agg_k<<<NN / 4, 256, 0, stream>>>(S1, cnt, cs, S2);
    // out = z * (g2 @ W_g2 + b_g2)                        S2 -> d_out (fp32, nt)
    gemm_k<2, 2><<<GB0, 256, 0, stream>>>(S2, Wt2, b_g2, nullptr, flag, z, d_out);
}

// Round 21
// 553.405 us; speedup vs baseline: 1.0212x; 1.0212x over previous
//
#include <hip/hip_runtime.h>
#include <stdint.h>

#define NN 100000
#define EE 1600000
#define DD 256
#define GB0 1563            // gemm blocks: (NN+63)/64
#define NFILL 1024          // fill blocks (NSUB*8)
#define NSUB 128

typedef __bf16 bf16;
typedef __attribute__((ext_vector_type(8))) __bf16 bf16x8;
typedef __attribute__((ext_vector_type(4))) float f32x4;
typedef __attribute__((ext_vector_type(4))) unsigned int u32x4;
typedef __attribute__((ext_vector_type(8))) unsigned short u16x8;

typedef __attribute__((address_space(1))) const unsigned int g_u32c;
typedef __attribute__((address_space(3))) unsigned int lds_u32;

__device__ __forceinline__ float bflo(unsigned int u) {
    union { unsigned int u; float f; } x; x.u = u << 16; return x.f;
}
__device__ __forceinline__ float bfhi(unsigned int u) {
    union { unsigned int u; float f; } x; x.u = u & 0xFFFF0000u; return x.f;
}
__device__ __forceinline__ unsigned short f2bf(float f) {
    return __builtin_bit_cast(unsigned short, (__bf16)f);
}

// ---------------------------------------------------------------------------
// fillprep: blocks [0,NFILL) = direct-slot CSR fill (dst-partitioned by XCD,
// scan-free: atomic cursor IS the degree); blocks [NFILL,NFILL+193) = weight
// transpose-cvt (192) + mask probe (1).
// ---------------------------------------------------------------------------
__global__ __launch_bounds__(256) void fillprep_k(
    const int* __restrict__ src, const int* __restrict__ dst,
    int* __restrict__ cnt, int* __restrict__ cs,
    const float* __restrict__ W0, const float* __restrict__ W1,
    const float* __restrict__ W2, bf16* __restrict__ T0,
    bf16* __restrict__ T1, bf16* __restrict__ T2,
    const unsigned int* __restrict__ m, int* __restrict__ flag) {
    int b = blockIdx.x;
    if (b < NFILL) {
        int prt = b & 7;
        int sub = b >> 3;
        int lo = prt * (NN >> 3);
        int hi = (prt == 7) ? NN : lo + (NN >> 3);
        const int per = EE / NSUB;
        int e0 = sub * per;
        int e1 = (sub == NSUB - 1) ? EE : e0 + per;
        for (int e = e0 + threadIdx.x; e < e1; e += 256) {
            int d = dst[e];
            if (d >= lo && d < hi) {
                int s = src[e];
                int slot = atomicAdd(&cnt[d], 1);
                if (slot < 64) cs[(d << 6) + slot] = s;   // P(overflow) ~ 5e-14
            }
        }
        return;
    }
    b -= NFILL;
    if (b == 192) {
        if (threadIdx.x < 64) {
            unsigned int v = m[threadIdx.x];
            int bad = (v > 1u && v != 0x3F800000u) ? 1 : 0;
            unsigned long long bl = __ballot(bad);
            if (threadIdx.x == 0) *flag = (bl != 0ull) ? 1 : 0;
        }
        return;
    }
    const float* W = b < 64 ? W0 : (b < 128 ? W1 : W2);
    bf16*       T  = b < 64 ? T0 : (b < 128 ? T1 : T2);
    int bb = b & 63;
    __shared__ float tile[32][33];
    int bx = bb & 7, by = bb >> 3;
    int tx = threadIdx.x & 31, ty = threadIdx.x >> 5;
    #pragma unroll
    for (int r = 0; r < 32; r += 8)
        tile[ty + r][tx] = W[(size_t)(by * 32 + ty + r) * DD + bx * 32 + tx];
    __syncthreads();
    #pragma unroll
    for (int r = 0; r < 32; r += 8)
        T[(size_t)(bx * 32 + ty + r) * DD + by * 32 + tx] = (bf16)tile[tx][ty + r];
}

// ---------------------------------------------------------------------------
// GEMM body (R16/R19-proven): 64x256 tile, BK=64, 2 barriers per K-step,
// XOR-swizzled LDS (rule 21: linear gload_lds dest + swizzled global source,
// reads at (kk*4+lk)^(lr&7)); swapped-operand MFMA -> 4 consecutive output
// cols per lane -> vector epilogue.
// EPI 1: +bias, relu, dropout(mask) -> bf16.  EPI 2: +bias, *z -> fp32 nt.
// ---------------------------------------------------------------------------
template <int EPI, int F32A>
__device__ __forceinline__ void gemm_body(
    const void* __restrict__ Ap, const bf16* __restrict__ Wt,
    const float* __restrict__ bias, const void* __restrict__ mask,
    const int* __restrict__ flagp, const float* __restrict__ z,
    void* __restrict__ outp, bf16* As, bf16* Bs, int m0) {
    int tid = threadIdx.x;
    int wid = tid >> 6, lane = tid & 63;
    int lr = lane & 15, lk = lane >> 4;
    int rx = lr & 7;

    f32x4 acc[4][4] = {};

    for (int k0 = 0; k0 < DD; k0 += 64) {
        #pragma unroll
        for (int i = 0; i < 2; i++) {
            int f = i * 256 + tid;
            int row = f >> 3;
            int cl  = f & 7;
            int cg  = cl ^ (row & 7);
            int gr = m0 + row; if (gr > NN - 1) gr = NN - 1;
            if (F32A) {
                const float* sp = (const float*)Ap + (size_t)gr * DD + k0 + cl * 8;
                float4 v0 = *(const float4*)sp;
                float4 v1 = *(const float4*)(sp + 4);
                u16x8 o = { f2bf(v0.x), f2bf(v0.y), f2bf(v0.z), f2bf(v0.w),
                            f2bf(v1.x), f2bf(v1.y), f2bf(v1.z), f2bf(v1.w) };
                *(u16x8*)(As + row * 64 + cg * 8) = o;
            } else {
                __builtin_amdgcn_global_load_lds(
                    (g_u32c*)((const bf16*)Ap + (size_t)gr * DD + k0 + cg * 8),
                    (lds_u32*)(As + (size_t)f * 8), 16, 0, 0);
            }
        }
        #pragma unroll
        for (int i = 0; i < 8; i++) {
            int f = i * 256 + tid;
            int row = f >> 3;
            int cg  = (f & 7) ^ (row & 7);
            __builtin_amdgcn_global_load_lds(
                (g_u32c*)(Wt + (size_t)row * DD + k0 + cg * 8),
                (lds_u32*)(Bs + (size_t)f * 8), 16, 0, 0);
        }
        __syncthreads();
        #pragma unroll
        for (int kk = 0; kk < 2; kk++) {
            bf16x8 af[4], bfr[4];
            #pragma unroll
            for (int mi = 0; mi < 4; mi++)
                af[mi] = *(const bf16x8*)(As + (mi * 16 + lr) * 64 + (((kk * 4 + lk) ^ rx) * 8));
            #pragma unroll
            for (int ni = 0; ni < 4; ni++)
                bfr[ni] = *(const bf16x8*)(Bs + (wid * 64 + ni * 16 + lr) * 64 + (((kk * 4 + lk) ^ rx) * 8));
            #pragma unroll
            for (int mi = 0; mi < 4; mi++)
                #pragma unroll
                for (int ni = 0; ni < 4; ni++)
                    acc[mi][ni] = __builtin_amdgcn_mfma_f32_16x16x32_bf16(
                        bfr[ni], af[mi], acc[mi][ni], 0, 0, 0);   // swapped
        }
        __syncthreads();
    }

    int bm = (EPI == 1) ? *flagp : 0;
    #pragma unroll
    for (int mi = 0; mi < 4; mi++) {
        int gr = m0 + mi * 16 + lr;
        if (gr >= NN) continue;
        #pragma unroll
        for (int ni = 0; ni < 4; ni++) {
            int gc = wid * 64 + ni * 16 + lk * 4;
            size_t idx = (size_t)gr * DD + gc;
            float4 b4 = *(const float4*)(bias + gc);
            float v0 = acc[mi][ni][0] + b4.x;
            float v1 = acc[mi][ni][1] + b4.y;
            float v2 = acc[mi][ni][2] + b4.z;
            float v3 = acc[mi][ni][3] + b4.w;
            if (EPI == 1) {
                v0 = fmaxf(v0, 0.f); v1 = fmaxf(v1, 0.f);
                v2 = fmaxf(v2, 0.f); v3 = fmaxf(v3, 0.f);
                if (bm) {
                    uchar4 u = *(const uchar4*)((const unsigned char*)mask + idx);
                    v0 *= u.x ? 2.f : 0.f; v1 *= u.y ? 2.f : 0.f;
                    v2 *= u.z ? 2.f : 0.f; v3 *= u.w ? 2.f : 0.f;
                } else {
                    uint4 u = *(const uint4*)((const unsigned int*)mask + idx);
                    v0 *= u.x ? 2.f : 0.f; v1 *= u.y ? 2.f : 0.f;
                    v2 *= u.z ? 2.f : 0.f; v3 *= u.w ? 2.f : 0.f;
                }
                ushort4 o = { f2bf(v0), f2bf(v1), f2bf(v2), f2bf(v3) };
                *(ushort4*)((unsigned short*)outp + idx) = o;
            } else {
                f32x4 zz = __builtin_nontemporal_load((const f32x4*)(z + idx));
                f32x4 o = { v0 * zz.x, v1 * zz.y, v2 * zz.z, v3 * zz.w };
                __builtin_nontemporal_store(o, (f32x4*)((float*)outp + idx));
            }
        }
    }
}

__global__ __launch_bounds__(256) void gemm0_k(
    const float* __restrict__ omega, const bf16* __restrict__ Wt,
    const float* __restrict__ bias, const void* __restrict__ mask,
    const int* __restrict__ flagp, bf16* __restrict__ outp) {
    __shared__ __align__(16) bf16 As[64 * 64];     // 8 KB
    __shared__ __align__(16) bf16 Bs[256 * 64];    // 32 KB
    int m0 = blockIdx.x * 64;
    if (m0 >= NN) return;
    gemm_body<1, 1>(omega, Wt, bias, mask, flagp, nullptr, outp, As, Bs, m0);
}

template <int ID, int EPI>
__global__ __launch_bounds__(256) void gemm_k(
    const bf16* __restrict__ Ap, const bf16* __restrict__ Wt,
    const float* __restrict__ bias, const void* __restrict__ mask,
    const int* __restrict__ flagp, const float* __restrict__ z,
    void* __restrict__ outp) {
    __shared__ __align__(16) bf16 As[64 * 64];
    __shared__ __align__(16) bf16 Bs[256 * 64];
    int m0 = blockIdx.x * 64;
    if (m0 >= NN) return;
    gemm_body<EPI, 0>(Ap, Wt, bias, mask, flagp, z, outp, As, Bs, m0);
}

// ---------------------------------------------------------------------------
// Slot-gather: out[n,:] = dinv[n] * ( sum_s dinv[s]*X[s,:] + dinv[n]*X[n,:] ).
// dinv computed on the fly: rsqrtf(cnt+1). cnt[n] <= 63 entries at cs[n*64..];
// single chunk, proven depth-4 pipeline; self-loop in fp32 epilogue.
// ---------------------------------------------------------------------------
#define AGG_GET(J, UVAR, MVAR)                                                   \
    {                                                                            \
        int _i = 2 * (J) + half;                                                 \
        int _s = __shfl(sl, _i & 63);                                            \
        float _w = __shfl(wl, _i & 63);                                          \
        MVAR = (_i < nume) ? _w : 0.f;                                           \
        UVAR = *(const u32x4*)(tb + (((size_t)(unsigned)_s) << 9) + lcoff);      \
    }
#define AGG_FMA(UVAR, MVAR)                                                      \
    {                                                                            \
        acc[0] = fmaf(MVAR, bflo(UVAR.x), acc[0]);                               \
        acc[1] = fmaf(MVAR, bfhi(UVAR.x), acc[1]);                               \
        acc[2] = fmaf(MVAR, bflo(UVAR.y), acc[2]);                               \
        acc[3] = fmaf(MVAR, bfhi(UVAR.y), acc[3]);                               \
        acc[4] = fmaf(MVAR, bflo(UVAR.z), acc[4]);                               \
        acc[5] = fmaf(MVAR, bfhi(UVAR.z), acc[5]);                               \
        acc[6] = fmaf(MVAR, bflo(UVAR.w), acc[6]);                               \
        acc[7] = fmaf(MVAR, bfhi(UVAR.w), acc[7]);                               \
    }

__global__ __launch_bounds__(256) void agg_k(
    const bf16* __restrict__ t, const int* __restrict__ cnt,
    const int* __restrict__ cs, bf16* __restrict__ out) {
    int node = blockIdx.x * 4 + (threadIdx.x >> 6);
    if (node >= NN) return;
    int lane = threadIdx.x & 63;
    int half = lane >> 5;
    int lc = lane & 31;
    int cn = cnt[node];
    int nume = cn > 63 ? 63 : cn;

    float acc[8] = {};
    const char* tb = (const char*)t;
    size_t lcoff = (size_t)(lc << 4);

    if (nume > 0) {
        int base = node << 6;
        int sl = 0; float wl = 0.f;
        if (lane < nume) {
            sl = __builtin_nontemporal_load(cs + base + lane);
            wl = rsqrtf((float)(cnt[sl] + 1));
        }
        int nit = (nume + 1) >> 1;

        u32x4 ua, ub, uc, ud;
        float ma, mb, mc, md;
        AGG_GET(0, ua, ma);
        AGG_GET(1, ub, mb);
        AGG_GET(2, uc, mc);
        int j = 0;
        for (; j + 3 < nit; j += 4) {
            AGG_GET(j + 3, ud, md); AGG_FMA(ua, ma);
            AGG_GET(j + 4, ua, ma); AGG_FMA(ub, mb);
            AGG_GET(j + 5, ub, mb); AGG_FMA(uc, mc);
            AGG_GET(j + 6, uc, mc); AGG_FMA(ud, md);
        }
        int rem = nit - j;
        if (rem > 0) AGG_FMA(ua, ma);
        if (rem > 1) AGG_FMA(ub, mb);
        if (rem > 2) AGG_FMA(uc, mc);
    }

    float dn = rsqrtf((float)(cn + 1));
    #pragma unroll
    for (int i = 0; i < 8; i++) acc[i] += __shfl_xor(acc[i], 32);
    if (half == 0) {
        // self-loop term: weight dinv[node] (then *dn below -> dinv^2)
        u32x4 u = *(const u32x4*)(tb + (((size_t)(unsigned)node) << 9) + lcoff);
        acc[0] = fmaf(dn, bflo(u.x), acc[0]);
        acc[1] = fmaf(dn, bfhi(u.x), acc[1]);
        acc[2] = fmaf(dn, bflo(u.y), acc[2]);
        acc[3] = fmaf(dn, bfhi(u.y), acc[3]);
        acc[4] = fmaf(dn, bflo(u.z), acc[4]);
        acc[5] = fmaf(dn, bfhi(u.z), acc[5]);
        acc[6] = fmaf(dn, bflo(u.w), acc[6]);
        acc[7] = fmaf(dn, bfhi(u.w), acc[7]);
        #pragma unroll
        for (int i = 0; i < 8; i++) acc[i] *= dn;
        u16x8 o = { f2bf(acc[0]), f2bf(acc[1]), f2bf(acc[2]), f2bf(acc[3]),
                    f2bf(acc[4]), f2bf(acc[5]), f2bf(acc[6]), f2bf(acc[7]) };
        __builtin_nontemporal_store(o, (u16x8*)((unsigned short*)out + (size_t)node * DD + lc * 8));
    }
}

// ---------------------------------------------------------------------------
extern "C" void kernel_launch(void* const* d_in, const int* in_sizes, int n_in,
                              void* d_out, int out_size, void* d_ws, size_t ws_size,
                              hipStream_t stream) {
    const float* z     = (const float*)d_in[0];
    const float* omega = (const float*)d_in[1];
    const int*   eidx  = (const int*)d_in[2];
    const float* W_lin = (const float*)d_in[3];
    const float* b_lin = (const float*)d_in[4];
    const float* W_g1  = (const float*)d_in[5];
    const float* b_g1  = (const float*)d_in[6];
    const float* W_g2  = (const float*)d_in[7];
    const float* b_g2  = (const float*)d_in[8];
    const void*  mask1 = d_in[9];
    const void*  mask2 = d_in[10];

    const int* e_src = eidx;
    const int* e_dst = eidx + EE;

    char* p = (char*)d_ws;
    size_t off = 0;
    auto alloc = [&](size_t bytes) -> char* {
        char* r = p + off;
        off = (off + bytes + 255) & ~(size_t)255;
        return r;
    };
    int*   flag = (int*)  alloc(4);
    int*   cnt  = (int*)  alloc((size_t)NN * 4);
    int*   cs   = (int*)  alloc((size_t)NN * 64 * 4);   // 25.6 MB slots
    bf16*  WtL  = (bf16*) alloc((size_t)DD * DD * 2);
    bf16*  Wt1  = (bf16*) alloc((size_t)DD * DD * 2);
    bf16*  Wt2  = (bf16*) alloc((size_t)DD * DD * 2);
    const size_t NBH = (size_t)NN * DD * 2;      // 51.2 MB bf16 slab
    bf16*  S1   = (bf16*) alloc(NBH);
    bf16*  S2   = (bf16*) alloc(NBH);

    // --- zero degree counters; fill CSR + weight-cvt + probe (one dispatch) ---
    (void)hipMemsetAsync(cnt, 0, (size_t)NN * 4, stream);
    fillprep_k<<<NFILL + 193, 256, 0, stream>>>(e_src, e_dst, cnt, cs,
                                                W_lin, W_g1, W_g2, WtL, Wt1, Wt2,
                                                (const unsigned int*)mask1, flag);

    // --- pipeline ---
    // h0 = dropout(relu(omega @ W_lin + b_lin))           omega(f32) -> S1
    gemm0_k<<<GB0, 256, 0, stream>>>(omega, WtL, b_lin, mask1, flag, S1);
    // g1 = dinv-weighted gather of S1 (+ self)            S1 -> S2
    agg_k<<<NN / 4, 256, 0, stream>>>(S1, cnt, cs, S2);
    // h1 = dropout(relu(g1 @ W_g1 + b_g1))                S2 -> S1
    gemm_k<1, 1><<<GB0, 256, 0, stream>>>(S2, Wt1, b_g1, mask2, flag, nullptr, S1);
    // g2 = dinv-weighted gather of S1 (+ self)            S1 -> S2
    agg_k<<<NN / 4, 256, 0, stream>>>(S1, cnt, cs, S2);
    // out = z * (g2 @ W_g2 + b_g2)                        S2 -> d_out (fp32, nt)
    gemm_k<2, 2><<<GB0, 256, 0, stream>>>(S2, Wt2, b_g2, nullptr, flag, z, d_out);
}